// Round 1
// baseline (16487.219 us; speedup 1.0000x reference)
//
#include <hip/hip_runtime.h>
#include <math.h>

// Problem dims
#define TIN 128
#define NB 64
#define TOUT 32
#define NV 32000
#define NE 512
#define NH 1024
#define NA 512
#define NL 4
#define H2 2048
#define H4 4096
#define XD 2560   // 2H + E
#define NCAT 3072 // 3H

// workspace offsets (in floats)
#define OFF_ENCP    0u
#define OFF_OUTPROJ 4194304u                  // 128*64*512
#define OFF_SCORES  (OFF_OUTPROJ + 32768u)    // 64*512
#define OFF_X       (OFF_SCORES + 8192u)      // 128*64
#define OFF_CAT2    (OFF_X + 163840u)         // 64*2560
#define OFF_PART    (OFF_CAT2 + 196608u)      // 64*3072
#define OFF_H       (OFF_PART + 3670016u)     // 14*64*4096
#define OFF_C       (OFF_H + 262144u)         // 4*64*1024
#define OFF_OPREV   (OFF_C + 262144u)
#define OFF_PP      (OFF_OPREV + 65536u)      // 64*1024
#define OFF_PTOK    (OFF_PP + 4096000u)       // 2*64*32000

// ---------------------------------------------------------------------------
// Generic fp32 block GEMM: 64 rows x 128 cols tile, K-sliced.
// A: [64][lda] rows (row-major, we read cols [k0, k0+klen))
// W: [K][ldw]  rows (row-major, we read cols [c0, c0+128))
// Each thread: 8m x 4n accumulators.
// ---------------------------------------------------------------------------
__device__ __forceinline__ void gemm64x128(
    const float* __restrict__ Ap, int lda,
    const float* __restrict__ Wp, int ldw,
    int k0, int klen, int c0, float acc[8][4])
{
  __shared__ float As[32][68];   // [k][m], pad 68 (16B-aligned rows)
  __shared__ float Ws[32][132];  // [k][n], pad 132 (16B-aligned rows)
  const int tid = threadIdx.x;
  const int n4 = (tid & 31) * 4;
  const int mg = (tid >> 5) * 8;

  for (int kt = 0; kt < klen; kt += 32) {
    const int kb = k0 + kt;
    // stage A tile: 64 m x 32 k  (512 float4)
#pragma unroll
    for (int r = 0; r < 2; ++r) {
      int f = tid + r * 256;          // 0..511
      int m = f >> 3;
      int kk = (f & 7) << 2;
      float4 v = *(const float4*)(Ap + (size_t)m * lda + kb + kk);
      As[kk + 0][m] = v.x; As[kk + 1][m] = v.y;
      As[kk + 2][m] = v.z; As[kk + 3][m] = v.w;
    }
    // stage W tile: 32 k x 128 n  (1024 float4)
#pragma unroll
    for (int r = 0; r < 4; ++r) {
      int f = tid + r * 256;          // 0..1023
      int kr = f >> 5;
      int cc = (f & 31) << 2;
      *(float4*)(&Ws[kr][cc]) =
          *(const float4*)(Wp + (size_t)(kb + kr) * ldw + c0 + cc);
    }
    __syncthreads();
#pragma unroll
    for (int k = 0; k < 32; ++k) {
      float4 w  = *(const float4*)(&Ws[k][n4]);
      float4 aa = *(const float4*)(&As[k][mg]);
      float4 ab = *(const float4*)(&As[k][mg + 4]);
      float av[8] = {aa.x, aa.y, aa.z, aa.w, ab.x, ab.y, ab.z, ab.w};
#pragma unroll
      for (int i = 0; i < 8; ++i) {
        acc[i][0] += av[i] * w.x;
        acc[i][1] += av[i] * w.y;
        acc[i][2] += av[i] * w.z;
        acc[i][3] += av[i] * w.w;
      }
    }
    __syncthreads();
  }
}

// ---------------------------------------------------------------------------
__global__ __launch_bounds__(256) void k_init(
    const float* __restrict__ h0, const float* __restrict__ c0,
    const float* __restrict__ o0, const int* __restrict__ eos,
    float* __restrict__ h, float* __restrict__ c,
    float* __restrict__ oprev, int* __restrict__ ptok)
{
  int i = blockIdx.x * 256 + threadIdx.x;
  if (i < NL * NB * NH) { h[i] = h0[i]; c[i] = c0[i]; }
  if (i < NB * NH) oprev[i] = o0[i];
  if (i < NB) ptok[i] = eos[0];
}

// enc_proj[t*B+b][a] = Enc[t*B+b][:] @ A1[H:][:,a]   (8192x2048 @ 2048x512)
__global__ __launch_bounds__(256) void k_encproj(
    const float* __restrict__ enc, const float* __restrict__ A1h,
    float* __restrict__ encp)
{
  int mt = blockIdx.x;  // 128 tiles of 64 rows
  int nt = blockIdx.y;  // 4 tiles of 128 cols
  float acc[8][4] = {};
  gemm64x128(enc + (size_t)mt * 64 * H2, H2, A1h, NA, 0, H2, nt * 128, acc);
  int n4 = (threadIdx.x & 31) * 4, mg = (threadIdx.x >> 5) * 8;
#pragma unroll
  for (int i = 0; i < 8; ++i)
    *(float4*)(encp + (size_t)(mt * 64 + mg + i) * NA + nt * 128 + n4) =
        make_float4(acc[i][0], acc[i][1], acc[i][2], acc[i][3]);
}

// outproj[b][a] = out_prev[b] @ A1[:H][:,a]; also x[b][2048+e] = emb[tok[b]][e]
__global__ __launch_bounds__(256) void k_outproj_emb(
    const float* __restrict__ oprev, const float* __restrict__ A1,
    const float* __restrict__ emb, const int* __restrict__ ptok,
    float* __restrict__ outproj, float* __restrict__ xbuf)
{
  int b = blockIdx.x, tid = threadIdx.x;
  __shared__ float ov[NH];
#pragma unroll
  for (int r = 0; r < 4; ++r) ov[tid + r * 256] = oprev[(size_t)b * NH + tid + r * 256];
  __syncthreads();
  float a0 = 0.f, a1 = 0.f;
  int c0 = tid, c1 = tid + 256;
#pragma unroll 8
  for (int k = 0; k < NH; ++k) {
    const float* row = A1 + (size_t)k * NA;
    float x = ov[k];
    a0 += x * row[c0];
    a1 += x * row[c1];
  }
  outproj[(size_t)b * NA + c0] = a0;
  outproj[(size_t)b * NA + c1] = a1;
  int tok = ptok[b];
  xbuf[(size_t)b * XD + H2 + c0] = emb[(size_t)tok * NE + c0];
  xbuf[(size_t)b * XD + H2 + c1] = emb[(size_t)tok * NE + c1];
}

// scores[t*B+b] = A2 . tanh(outproj[b] + encp[t*B+b] + b1) + b2 + mask
__global__ __launch_bounds__(256) void k_scores(
    const float* __restrict__ encp, const float* __restrict__ outproj,
    const float* __restrict__ b1, const float* __restrict__ A2,
    const float* __restrict__ b2, const float* __restrict__ ison,
    float* __restrict__ scores)
{
  int w = threadIdx.x >> 6, lane = threadIdx.x & 63;
  int idx = blockIdx.x * 4 + w;  // t*64 + b
  int b = idx & 63;
  const float* ep = encp + (size_t)idx * NA;
  const float* op = outproj + (size_t)b * NA;
  float acc = 0.f;
#pragma unroll
  for (int r = 0; r < 8; ++r) {
    int a = lane + r * 64;
    acc += tanhf(op[a] + ep[a] + b1[a]) * A2[a];
  }
#pragma unroll
  for (int off = 32; off; off >>= 1) acc += __shfl_down(acc, off);
  if (lane == 0)
    scores[idx] = acc + b2[0] + (1.0f - ison[idx]) * (-1e30f);
}

// per b: alpha = softmax_t(scores[:,b]); ctx[d] = sum_t alpha[t]*enc[t][b][d]
// writes ctx into x[b][0:2048] and cat2[b][1024:3072]
__global__ __launch_bounds__(256) void k_ctx(
    const float* __restrict__ scores, const float* __restrict__ enc,
    float* __restrict__ xbuf, float* __restrict__ cat2)
{
  int b = blockIdx.x, dc = blockIdx.y, tid = threadIdx.x;
  __shared__ float sv[TIN];
  __shared__ float sred;
  if (tid < TIN) sv[tid] = scores[tid * NB + b];
  __syncthreads();
  if (tid < 64) {
    float m = fmaxf(sv[tid], sv[tid + 64]);
#pragma unroll
    for (int off = 32; off; off >>= 1) m = fmaxf(m, __shfl_down(m, off));
    if (tid == 0) sred = m;
  }
  __syncthreads();
  float mx = sred;
  if (tid < TIN) sv[tid] = expf(sv[tid] - mx);
  __syncthreads();
  if (tid < 64) {
    float s = sv[tid] + sv[tid + 64];
#pragma unroll
    for (int off = 32; off; off >>= 1) s += __shfl_down(s, off);
    if (tid == 0) sred = 1.f / s;
  }
  __syncthreads();
  float inv = sred;

  int d0 = dc * 512 + tid * 2;
  const float* eb = enc + (size_t)b * H2 + d0;
  float ax = 0.f, ay = 0.f;
#pragma unroll 4
  for (int t = 0; t < TIN; ++t) {
    float al = sv[t];
    float2 ev = *(const float2*)(eb + (size_t)t * NB * H2);
    ax += al * ev.x;
    ay += al * ev.y;
  }
  float2 o; o.x = ax * inv; o.y = ay * inv;
  *(float2*)(xbuf + (size_t)b * XD + d0) = o;
  *(float2*)(cat2 + (size_t)b * NCAT + NH + d0) = o;
}

// LSTM gates partial GEMM: two segments (inp@W_ih, h_old@W_hh), K-split by 256
__global__ __launch_bounds__(256) void k_gates(
    const float* __restrict__ A1p, int lda1, int ns1,
    const float* __restrict__ W1p, const float* __restrict__ A2p,
    const float* __restrict__ W2p, float* __restrict__ part)
{
  int cs = blockIdx.x, ks = blockIdx.y;
  const float* Ap; const float* Wp; int lda, k0;
  if (ks < ns1) { Ap = A1p; Wp = W1p; lda = lda1; k0 = ks * 256; }
  else          { Ap = A2p; Wp = W2p; lda = NH;  k0 = (ks - ns1) * 256; }
  float acc[8][4] = {};
  gemm64x128(Ap, lda, Wp, H4, k0, 256, cs * 128, acc);
  int n4 = (threadIdx.x & 31) * 4, mg = (threadIdx.x >> 5) * 8;
  float* po = part + (size_t)ks * NB * H4;
#pragma unroll
  for (int i = 0; i < 8; ++i)
    *(float4*)(po + (size_t)(mg + i) * H4 + cs * 128 + n4) =
        make_float4(acc[i][0], acc[i][1], acc[i][2], acc[i][3]);
}

// reduce partials + biases + LSTM cell update for layer l
__global__ __launch_bounds__(256) void k_cell(
    const float* __restrict__ part, int S,
    const float* __restrict__ bih, const float* __restrict__ bhh, int l,
    float* __restrict__ h, float* __restrict__ c,
    float* __restrict__ cat2, float* __restrict__ oprev, int last)
{
  int b = blockIdx.x, tid = threadIdx.x;
#pragma unroll
  for (int j = 0; j < 4; ++j) {
    int hc = j * 256 + tid;
    float gi = 0.f, gf = 0.f, gg = 0.f, go = 0.f;
    for (int s = 0; s < S; ++s) {
      const float* p = part + ((size_t)s * NB + b) * H4;
      gi += p[hc]; gf += p[NH + hc]; gg += p[2 * NH + hc]; go += p[3 * NH + hc];
    }
    const float* bi = bih + (size_t)l * H4;
    const float* bh = bhh + (size_t)l * H4;
    gi += bi[hc] + bh[hc];
    gf += bi[NH + hc] + bh[NH + hc];
    gg += bi[2 * NH + hc] + bh[2 * NH + hc];
    go += bi[3 * NH + hc] + bh[3 * NH + hc];
    size_t off = ((size_t)l * NB + b) * NH + hc;
    float cold = c[off];
    float si = 1.f / (1.f + expf(-gi));
    float sf = 1.f / (1.f + expf(-gf));
    float so = 1.f / (1.f + expf(-go));
    float cn = sf * cold + si * tanhf(gg);
    float hn = so * tanhf(cn);
    c[off] = cn; h[off] = hn;
    if (last) {
      cat2[(size_t)b * NCAT + hc] = hn;
      oprev[(size_t)b * NH + hc] = hn;
    }
  }
}

// final logits partial GEMM: cat2[64][3072] @ Wl[3072][32000], K-split by 1536
__global__ __launch_bounds__(256) void k_final(
    const float* __restrict__ cat2, const float* __restrict__ Wl,
    float* __restrict__ pp)
{
  int cs = blockIdx.x, ks = blockIdx.y;
  float acc[8][4] = {};
  gemm64x128(cat2, NCAT, Wl, NV, ks * 1536, 1536, cs * 128, acc);
  int n4 = (threadIdx.x & 31) * 4, mg = (threadIdx.x >> 5) * 8;
  float* po = pp + (size_t)ks * NB * NV;
#pragma unroll
  for (int i = 0; i < 8; ++i)
    *(float4*)(po + (size_t)(mg + i) * NV + cs * 128 + n4) =
        make_float4(acc[i][0], acc[i][1], acc[i][2], acc[i][3]);
}

// per b: logits = relu(pp0+pp1+bl); softmax -> d_out; argmax -> ptok
__global__ __launch_bounds__(1024) void k_softmax(
    const float* __restrict__ pp, const float* __restrict__ bl,
    float* __restrict__ dout, int step, int* __restrict__ ptok)
{
  int b = blockIdx.x, tid = threadIdx.x;
  int lane = tid & 63, wid = tid >> 6;
  const float* p0 = pp + (size_t)b * NV;
  const float* p1 = pp + (size_t)NB * NV + (size_t)b * NV;
  __shared__ float wred[16];
  __shared__ int wredi[16];
  __shared__ float s_max, s_inv;
  __shared__ int s_idx;

  float bm = -1.f; int bi = 0;
  for (int v = tid; v < NV; v += 1024) {
    float val = fmaxf(p0[v] + p1[v] + bl[v], 0.f);
    if (val > bm) { bm = val; bi = v; }
  }
#pragma unroll
  for (int off = 32; off; off >>= 1) {
    float om = __shfl_down(bm, off);
    int oi = __shfl_down(bi, off);
    if (om > bm || (om == bm && oi < bi)) { bm = om; bi = oi; }
  }
  if (lane == 0) { wred[wid] = bm; wredi[wid] = bi; }
  __syncthreads();
  if (wid == 0) {
    float m = (lane < 16) ? wred[lane] : -2.f;
    int ix = (lane < 16) ? wredi[lane] : 0;
#pragma unroll
    for (int off = 8; off; off >>= 1) {
      float om = __shfl_down(m, off);
      int oi = __shfl_down(ix, off);
      if (om > m || (om == m && oi < ix)) { m = om; ix = oi; }
    }
    if (lane == 0) { s_max = m; s_idx = ix; }
  }
  __syncthreads();
  float mx = s_max;
  float ls = 0.f;
  for (int v = tid; v < NV; v += 1024) {
    float val = fmaxf(p0[v] + p1[v] + bl[v], 0.f);
    ls += expf(val - mx);
  }
#pragma unroll
  for (int off = 32; off; off >>= 1) ls += __shfl_down(ls, off);
  if (lane == 0) wred[wid] = ls;
  __syncthreads();
  if (wid == 0) {
    float s = (lane < 16) ? wred[lane] : 0.f;
#pragma unroll
    for (int off = 8; off; off >>= 1) s += __shfl_down(s, off);
    if (lane == 0) s_inv = 1.f / s;
  }
  __syncthreads();
  float inv = s_inv;
  float* o = dout + ((size_t)step * NB + b) * NV;
  for (int v = tid; v < NV; v += 1024) {
    float val = fmaxf(p0[v] + p1[v] + bl[v], 0.f);
    o[v] = expf(val - mx) * inv;
  }
  if (tid == 0) ptok[b] = s_idx;
}

// ---------------------------------------------------------------------------
extern "C" void kernel_launch(void* const* d_in, const int* in_sizes, int n_in,
                              void* d_out, int out_size, void* d_ws, size_t ws_size,
                              hipStream_t stream)
{
  (void)in_sizes; (void)n_in; (void)out_size; (void)ws_size;
  const float* enc  = (const float*)d_in[0];
  const float* ison = (const float*)d_in[1];
  const float* emb  = (const float*)d_in[2];
  const float* A1   = (const float*)d_in[3];
  const float* b1   = (const float*)d_in[4];
  const float* A2   = (const float*)d_in[5];
  const float* b2   = (const float*)d_in[6];
  const float* Wih0 = (const float*)d_in[7];
  const float* WihR = (const float*)d_in[8];
  const float* Whh  = (const float*)d_in[9];
  const float* bih  = (const float*)d_in[10];
  const float* bhh  = (const float*)d_in[11];
  const float* Wl   = (const float*)d_in[12];
  const float* bl   = (const float*)d_in[13];
  const float* h0   = (const float*)d_in[14];
  const float* c0   = (const float*)d_in[15];
  const float* o0   = (const float*)d_in[16];
  const int*   eos  = (const int*)d_in[17];

  float* ws      = (float*)d_ws;
  float* encp    = ws + OFF_ENCP;
  float* outproj = ws + OFF_OUTPROJ;
  float* scores  = ws + OFF_SCORES;
  float* xbuf    = ws + OFF_X;
  float* cat2    = ws + OFF_CAT2;
  float* part    = ws + OFF_PART;
  float* hbuf    = ws + OFF_H;
  float* cbuf    = ws + OFF_C;
  float* oprev   = ws + OFF_OPREV;
  float* pp      = ws + OFF_PP;
  int*   ptok    = (int*)(ws + OFF_PTOK);

  k_init<<<1024, 256, 0, stream>>>(h0, c0, o0, eos, hbuf, cbuf, oprev, ptok);
  k_encproj<<<dim3(128, 4), 256, 0, stream>>>(enc, A1 + (size_t)NH * NA, encp);

  for (int s = 0; s < TOUT; ++s) {
    k_outproj_emb<<<NB, 256, 0, stream>>>(oprev, A1, emb, ptok, outproj, xbuf);
    k_scores<<<2048, 256, 0, stream>>>(encp, outproj, b1, A2, b2, ison, scores);
    k_ctx<<<dim3(NB, 4), 256, 0, stream>>>(scores, enc, xbuf, cat2);

    // layer 0: inp = x (K=2560, 10 slices) + h[0]@W_hh (4 slices)
    k_gates<<<dim3(32, 14), 256, 0, stream>>>(xbuf, XD, 10, Wih0, hbuf, Whh, part);
    k_cell<<<NB, 256, 0, stream>>>(part, 14, bih, bhh, 0, hbuf, cbuf, cat2, oprev, 0);
    for (int l = 1; l < NL; ++l) {
      k_gates<<<dim3(32, 8), 256, 0, stream>>>(
          hbuf + (size_t)(l - 1) * NB * NH, NH, 4,
          WihR + (size_t)(l - 1) * NH * H4,
          hbuf + (size_t)l * NB * NH,
          Whh + (size_t)l * NH * H4, part);
      k_cell<<<NB, 256, 0, stream>>>(part, 8, bih, bhh, l, hbuf, cbuf, cat2, oprev,
                                     (l == NL - 1) ? 1 : 0);
    }

    k_final<<<dim3(250, 2), 256, 0, stream>>>(cat2, Wl, pp);
    k_softmax<<<NB, 1024, 0, stream>>>(pp, bl, (float*)d_out, s, ptok);
  }
}